// Round 7
// baseline (285.786 us; speedup 1.0000x reference)
//
#include <hip/hip_runtime.h>

#define N_NODES 100000
#define N_EDGES 1000000
#define EPS 1e-5f
#define SLOPE 0.01f
#define CAP 20       // payload slots per node; Poisson(10) -> ~275 overflow edges
#define OVF_CAP 32768
#define NBLK 391     // ceil(N_NODES/256)
#define GBLK 1563    // ceil(N_NODES*5/320)

// 32B-aligned payload: both stores hit ONE random 32B sector.
struct __align__(32) Pay { float4 ef; int src; };

// ---------------------------------------------------------------------------
// ws layout: pay (N*CAP*32B = 64 MB) | S (N*80 f, 32 MB) |
//            cnt (N int) + stats(32 f) + ovf_cnt(1 int) [zeroed] | ovf list
// total ~96.5 MB
// ---------------------------------------------------------------------------

// K1: single-pass bucket scatter. cnt fetch-add doubles as degree count.
__global__ __launch_bounds__(256) void payload_kernel(
    const int* __restrict__ edge_index,
    const float* __restrict__ efeat,
    int* __restrict__ cnt,
    Pay* __restrict__ pay,
    int* __restrict__ ovf,
    int* __restrict__ ovf_cnt)
{
    int eid = blockIdx.x * 256 + threadIdx.x;
    if (eid >= N_EDGES) return;
    int src = edge_index[eid];
    int dst = edge_index[N_EDGES + eid];
    float4 ef = *(const float4*)(efeat + (size_t)eid * 4);
    int r = atomicAdd(cnt + dst, 1);
    if (r < CAP) {
        Pay* p = pay + (size_t)dst * CAP + r;
        p->ef = ef;
        p->src = src;
    } else {
        int o = atomicAdd(ovf_cnt, 1);
        if (o < OVF_CAP) ovf[o] = eid;
    }
}

// ---------------------------------------------------------------------------
// K2: S[n] = sum over bucketed edges of outer(v[src], [1, ef]).
// 5 threads/node, natural order; thread t owns component t (16 floats).
// pay rows stream sequentially; only v[src] is random (6.4 MB, cache-warm).
// ---------------------------------------------------------------------------
__global__ __launch_bounds__(320) void gather_s_kernel(
    const float* __restrict__ v,
    const Pay* __restrict__ pay,
    const int* __restrict__ cnt,
    float* __restrict__ S)
{
    int tid = blockIdx.x * 320 + threadIdx.x;
    int n = tid / 5;
    int t = tid % 5;
    if (n >= N_NODES) return;

    int deg = min(cnt[n], CAP);
    const Pay* row = pay + (size_t)n * CAP;

    float acc[16];
    #pragma unroll
    for (int i = 0; i < 16; ++i) acc[i] = 0.0f;

    for (int j = 0; j < deg; ++j) {
        float4 ef = row[j].ef;
        int src = row[j].src;
        float c = 1.0f;
        c = (t == 1) ? ef.x : c;
        c = (t == 2) ? ef.y : c;
        c = (t == 3) ? ef.z : c;
        c = (t == 4) ? ef.w : c;
        const float* vp = v + (size_t)src * 16;
        #pragma unroll
        for (int i = 0; i < 4; ++i) {
            float4 tv = *(const float4*)(vp + i * 4);
            acc[i*4+0] = fmaf(c, tv.x, acc[i*4+0]);
            acc[i*4+1] = fmaf(c, tv.y, acc[i*4+1]);
            acc[i*4+2] = fmaf(c, tv.z, acc[i*4+2]);
            acc[i*4+3] = fmaf(c, tv.w, acc[i*4+3]);
        }
    }

    float* sp = S + (size_t)n * 80 + t * 16;
    #pragma unroll
    for (int i = 0; i < 4; ++i)
        *(float4*)(sp + i * 4) = make_float4(acc[i*4+0], acc[i*4+1],
                                             acc[i*4+2], acc[i*4+3]);
}

// K3: fold the (rare) overflow edges into S with fp atomics. ~0-300 edges.
__global__ __launch_bounds__(256) void ovf_kernel(
    const float* __restrict__ v,
    const int* __restrict__ edge_index,
    const float* __restrict__ efeat,
    const int* __restrict__ ovf,
    const int* __restrict__ ovf_cnt,
    float* __restrict__ S)
{
    int m = min(*ovf_cnt, OVF_CAP);
    for (int i = threadIdx.x; i < m; i += 256) {
        int eid = ovf[i];
        int src = edge_index[eid];
        int dst = edge_index[N_EDGES + eid];
        float4 ef = *(const float4*)(efeat + (size_t)eid * 4);
        float cc[5] = {1.0f, ef.x, ef.y, ef.z, ef.w};
        const float* vp = v + (size_t)src * 16;
        float* sp = S + (size_t)dst * 80;
        #pragma unroll
        for (int t = 0; t < 5; ++t)
            for (int k = 0; k < 16; ++k)
                unsafeAtomicAdd(sp + t * 16 + k, cc[t] * vp[k]);
    }
}

// ---------------------------------------------------------------------------
// K4: per-node: msg = (S0*B + sum_k Sk*Wk)/deg; + root*v + bias -> out;
// per-column sum/sumsq -> stats. Weight indices wave-uniform -> SGPR folds.
// ---------------------------------------------------------------------------
__global__ __launch_bounds__(256) void node_kernel(
    const float* __restrict__ v,
    const float* __restrict__ S,
    const int* __restrict__ cnt,
    const float* __restrict__ enet_w,
    const float* __restrict__ enet_b,
    const float* __restrict__ root,
    const float* __restrict__ bias,
    float* __restrict__ out,
    float* __restrict__ stats)
{
    int n = blockIdx.x * 256 + threadIdx.x;
    bool active = (n < N_NODES);

    float val[16];
    if (active) {
        float s[80];
        #pragma unroll
        for (int i = 0; i < 20; ++i) {
            float4 tv = *(const float4*)(S + (size_t)n * 80 + i * 4);
            s[i*4+0] = tv.x; s[i*4+1] = tv.y; s[i*4+2] = tv.z; s[i*4+3] = tv.w;
        }
        float vn[16];
        #pragma unroll
        for (int i = 0; i < 4; ++i) {
            float4 tv = *(const float4*)(v + (size_t)n * 16 + i * 4);
            vn[i*4+0] = tv.x; vn[i*4+1] = tv.y; vn[i*4+2] = tv.z; vn[i*4+3] = tv.w;
        }
        float scale = 1.0f / fmaxf((float)cnt[n], 1.0f);

        #pragma unroll
        for (int o = 0; o < 16; ++o) {
            float a = 0.0f;
            #pragma unroll
            for (int i = 0; i < 16; ++i) {
                a = fmaf(s[i], enet_b[i * 16 + o], a);           // S0 * B
                #pragma unroll
                for (int k = 0; k < 4; ++k)
                    a = fmaf(s[16 + k * 16 + i],
                             enet_w[(i * 16 + o) * 4 + k], a);   // Sk * Wk
            }
            a = fmaf(a, scale, bias[o]);
            #pragma unroll
            for (int i = 0; i < 16; ++i)
                a = fmaf(vn[i], root[i * 16 + o], a);
            val[o] = a;
        }
        #pragma unroll
        for (int i = 0; i < 4; ++i)
            *(float4*)(out + (size_t)n * 16 + i * 4) =
                make_float4(val[i*4+0], val[i*4+1], val[i*4+2], val[i*4+3]);
    } else {
        #pragma unroll
        for (int o = 0; o < 16; ++o) val[o] = 0.0f;
    }

    float ssum[16], ssq[16];
    #pragma unroll
    for (int o = 0; o < 16; ++o) {
        float a = val[o];
        float b = a * a;
        #pragma unroll
        for (int m = 1; m < 64; m <<= 1) {
            a += __shfl_xor(a, m, 64);
            b += __shfl_xor(b, m, 64);
        }
        ssum[o] = a; ssq[o] = b;
    }
    __shared__ float part[4][32];
    int wave = threadIdx.x >> 6;
    int lane = threadIdx.x & 63;
    if (lane == 0) {
        #pragma unroll
        for (int o = 0; o < 16; ++o) {
            part[wave][o] = ssum[o];
            part[wave][16 + o] = ssq[o];
        }
    }
    __syncthreads();
    if (threadIdx.x < 32) {
        float t = part[0][threadIdx.x] + part[1][threadIdx.x] +
                  part[2][threadIdx.x] + part[3][threadIdx.x];
        unsafeAtomicAdd(stats + threadIdx.x, t);
    }
}

// K5: BatchNorm (batch stats) + LeakyReLU, in place on d_out.
__global__ __launch_bounds__(256) void final_kernel(
    float* __restrict__ out,
    const float* __restrict__ stats,
    const float* __restrict__ gamma,
    const float* __restrict__ beta)
{
    int idx = blockIdx.x * 256 + threadIdx.x;
    if (idx >= N_NODES * 16) return;
    int o = idx & 15;
    const float invN = 1.0f / (float)N_NODES;
    float mu = stats[o] * invN;
    float var = stats[16 + o] * invN - mu * mu;
    var = fmaxf(var, 0.0f);
    float x = out[idx];
    float y = fmaf(gamma[o] * (x - mu), rsqrtf(var + EPS), beta[o]);
    out[idx] = (y >= 0.0f) ? y : SLOPE * y;
}

extern "C" void kernel_launch(void* const* d_in, const int* in_sizes, int n_in,
                              void* d_out, int out_size, void* d_ws, size_t ws_size,
                              hipStream_t stream)
{
    const float* v = (const float*)d_in[0];
    const float* e = (const float*)d_in[1];
    const int* edge_index = (const int*)d_in[2];
    const float* enet_w = (const float*)d_in[3];
    const float* enet_b = (const float*)d_in[4];
    const float* root = (const float*)d_in[5];
    const float* bias = (const float*)d_in[6];
    const float* gamma = (const float*)d_in[7];
    const float* beta = (const float*)d_in[8];
    float* out = (float*)d_out;

    char* ws = (char*)d_ws;
    Pay*   pay     = (Pay*)ws;     ws += (size_t)N_NODES * CAP * sizeof(Pay); // 64 MB
    float* S       = (float*)ws;   ws += (size_t)N_NODES * 80 * 4;            // 32 MB
    int*   cnt     = (int*)ws;     ws += (size_t)N_NODES * 4;
    float* stats   = (float*)ws;   ws += 32 * 4;
    int*   ovf_cnt = (int*)ws;     ws += 4;
    int*   ovf     = (int*)ws;

    // zero cnt + stats + ovf_cnt (contiguous)
    hipMemsetAsync(cnt, 0, (size_t)N_NODES * 4 + 32 * 4 + 4, stream);

    payload_kernel<<<(N_EDGES + 255) / 256, 256, 0, stream>>>(
        edge_index, e, cnt, pay, ovf, ovf_cnt);
    gather_s_kernel<<<GBLK, 320, 0, stream>>>(v, pay, cnt, S);
    ovf_kernel<<<1, 256, 0, stream>>>(v, edge_index, e, ovf, ovf_cnt, S);
    node_kernel<<<NBLK, 256, 0, stream>>>(
        v, S, cnt, enet_w, enet_b, root, bias, out, stats);
    final_kernel<<<(N_NODES * 16 + 255) / 256, 256, 0, stream>>>(
        out, stats, gamma, beta);
}

// Round 8
// 275.099 us; speedup vs baseline: 1.0388x; 1.0388x over previous
//
#include <hip/hip_runtime.h>

#define N_NODES 100000
#define N_EDGES 1000000
#define EPS 1e-5f
#define SLOPE 0.01f
#define CAP 20       // payload slots per node; Poisson(10) -> ~275 overflow edges
#define OVF_CAP 32768
#define NBLK 391     // ceil(N_NODES/256)
#define GBLK 1563    // ceil(N_NODES*5/320)

// 32B-aligned payload: both stores hit ONE random 32B sector.
struct __align__(32) Pay { float4 ef; int src; };

// ---------------------------------------------------------------------------
// ws layout: pay (N*CAP*32B = 64 MB) | S (N*80 f, 32 MB) |
//            cnt (N int) + stats(32 f) + ovf_cnt(1 int) [zeroed] | ovf list
// total ~96.5 MB
// ---------------------------------------------------------------------------

// K1: single-pass bucket scatter. cnt fetch-add doubles as degree count.
__global__ __launch_bounds__(256) void payload_kernel(
    const int* __restrict__ edge_index,
    const float* __restrict__ efeat,
    int* __restrict__ cnt,
    Pay* __restrict__ pay,
    int* __restrict__ ovf,
    int* __restrict__ ovf_cnt)
{
    int eid = blockIdx.x * 256 + threadIdx.x;
    if (eid >= N_EDGES) return;
    int src = edge_index[eid];
    int dst = edge_index[N_EDGES + eid];
    float4 ef = *(const float4*)(efeat + (size_t)eid * 4);
    int r = atomicAdd(cnt + dst, 1);
    if (r < CAP) {
        Pay* p = pay + (size_t)dst * CAP + r;
        p->ef = ef;
        p->src = src;
    } else {
        int o = atomicAdd(ovf_cnt, 1);
        if (o < OVF_CAP) ovf[o] = eid;
    }
}

// ---------------------------------------------------------------------------
// K2: S[n] = sum over bucketed edges of outer(v[src], [1, ef]).
// 5 threads/node, natural order; thread t owns component t (16 floats).
// pay rows stream sequentially; only v[src] is random (6.4 MB, cache-warm).
// ---------------------------------------------------------------------------
__global__ __launch_bounds__(320) void gather_s_kernel(
    const float* __restrict__ v,
    const Pay* __restrict__ pay,
    const int* __restrict__ cnt,
    float* __restrict__ S)
{
    int tid = blockIdx.x * 320 + threadIdx.x;
    int n = tid / 5;
    int t = tid % 5;
    if (n >= N_NODES) return;

    int deg = min(cnt[n], CAP);
    const Pay* row = pay + (size_t)n * CAP;

    float acc[16];
    #pragma unroll
    for (int i = 0; i < 16; ++i) acc[i] = 0.0f;

    for (int j = 0; j < deg; ++j) {
        float4 ef = row[j].ef;
        int src = row[j].src;
        float c = 1.0f;
        c = (t == 1) ? ef.x : c;
        c = (t == 2) ? ef.y : c;
        c = (t == 3) ? ef.z : c;
        c = (t == 4) ? ef.w : c;
        const float* vp = v + (size_t)src * 16;
        #pragma unroll
        for (int i = 0; i < 4; ++i) {
            float4 tv = *(const float4*)(vp + i * 4);
            acc[i*4+0] = fmaf(c, tv.x, acc[i*4+0]);
            acc[i*4+1] = fmaf(c, tv.y, acc[i*4+1]);
            acc[i*4+2] = fmaf(c, tv.z, acc[i*4+2]);
            acc[i*4+3] = fmaf(c, tv.w, acc[i*4+3]);
        }
    }

    float* sp = S + (size_t)n * 80 + t * 16;
    #pragma unroll
    for (int i = 0; i < 4; ++i)
        *(float4*)(sp + i * 4) = make_float4(acc[i*4+0], acc[i*4+1],
                                             acc[i*4+2], acc[i*4+3]);
}

// K3: fold the (rare) overflow edges into S with fp atomics, grid-strided
// across 128 blocks (round-7 lesson: a single workgroup serializes ~22K
// atomics behind per-CU queue depth -> 73 us; spread them machine-wide).
__global__ __launch_bounds__(256) void ovf_kernel(
    const float* __restrict__ v,
    const int* __restrict__ edge_index,
    const float* __restrict__ efeat,
    const int* __restrict__ ovf,
    const int* __restrict__ ovf_cnt,
    float* __restrict__ S)
{
    int m = min(*ovf_cnt, OVF_CAP);
    for (int i = blockIdx.x * 256 + threadIdx.x; i < m; i += gridDim.x * 256) {
        int eid = ovf[i];
        int src = edge_index[eid];
        int dst = edge_index[N_EDGES + eid];
        float4 ef = *(const float4*)(efeat + (size_t)eid * 4);
        float cc[5] = {1.0f, ef.x, ef.y, ef.z, ef.w};
        const float* vp = v + (size_t)src * 16;
        float* sp = S + (size_t)dst * 80;
        #pragma unroll
        for (int t = 0; t < 5; ++t)
            #pragma unroll
            for (int k = 0; k < 16; ++k)
                unsafeAtomicAdd(sp + t * 16 + k, cc[t] * vp[k]);
    }
}

// ---------------------------------------------------------------------------
// K4: per-node: msg = (S0*B + sum_k Sk*Wk)/deg; + root*v + bias -> out;
// per-column sum/sumsq -> stats. Weight indices wave-uniform -> SGPR folds.
// ---------------------------------------------------------------------------
__global__ __launch_bounds__(256) void node_kernel(
    const float* __restrict__ v,
    const float* __restrict__ S,
    const int* __restrict__ cnt,
    const float* __restrict__ enet_w,
    const float* __restrict__ enet_b,
    const float* __restrict__ root,
    const float* __restrict__ bias,
    float* __restrict__ out,
    float* __restrict__ stats)
{
    int n = blockIdx.x * 256 + threadIdx.x;
    bool active = (n < N_NODES);

    float val[16];
    if (active) {
        float s[80];
        #pragma unroll
        for (int i = 0; i < 20; ++i) {
            float4 tv = *(const float4*)(S + (size_t)n * 80 + i * 4);
            s[i*4+0] = tv.x; s[i*4+1] = tv.y; s[i*4+2] = tv.z; s[i*4+3] = tv.w;
        }
        float vn[16];
        #pragma unroll
        for (int i = 0; i < 4; ++i) {
            float4 tv = *(const float4*)(v + (size_t)n * 16 + i * 4);
            vn[i*4+0] = tv.x; vn[i*4+1] = tv.y; vn[i*4+2] = tv.z; vn[i*4+3] = tv.w;
        }
        float scale = 1.0f / fmaxf((float)cnt[n], 1.0f);

        #pragma unroll
        for (int o = 0; o < 16; ++o) {
            float a = 0.0f;
            #pragma unroll
            for (int i = 0; i < 16; ++i) {
                a = fmaf(s[i], enet_b[i * 16 + o], a);           // S0 * B
                #pragma unroll
                for (int k = 0; k < 4; ++k)
                    a = fmaf(s[16 + k * 16 + i],
                             enet_w[(i * 16 + o) * 4 + k], a);   // Sk * Wk
            }
            a = fmaf(a, scale, bias[o]);
            #pragma unroll
            for (int i = 0; i < 16; ++i)
                a = fmaf(vn[i], root[i * 16 + o], a);
            val[o] = a;
        }
        #pragma unroll
        for (int i = 0; i < 4; ++i)
            *(float4*)(out + (size_t)n * 16 + i * 4) =
                make_float4(val[i*4+0], val[i*4+1], val[i*4+2], val[i*4+3]);
    } else {
        #pragma unroll
        for (int o = 0; o < 16; ++o) val[o] = 0.0f;
    }

    float ssum[16], ssq[16];
    #pragma unroll
    for (int o = 0; o < 16; ++o) {
        float a = val[o];
        float b = a * a;
        #pragma unroll
        for (int m = 1; m < 64; m <<= 1) {
            a += __shfl_xor(a, m, 64);
            b += __shfl_xor(b, m, 64);
        }
        ssum[o] = a; ssq[o] = b;
    }
    __shared__ float part[4][32];
    int wave = threadIdx.x >> 6;
    int lane = threadIdx.x & 63;
    if (lane == 0) {
        #pragma unroll
        for (int o = 0; o < 16; ++o) {
            part[wave][o] = ssum[o];
            part[wave][16 + o] = ssq[o];
        }
    }
    __syncthreads();
    if (threadIdx.x < 32) {
        float t = part[0][threadIdx.x] + part[1][threadIdx.x] +
                  part[2][threadIdx.x] + part[3][threadIdx.x];
        unsafeAtomicAdd(stats + threadIdx.x, t);
    }
}

// K5: BatchNorm (batch stats) + LeakyReLU, in place on d_out.
__global__ __launch_bounds__(256) void final_kernel(
    float* __restrict__ out,
    const float* __restrict__ stats,
    const float* __restrict__ gamma,
    const float* __restrict__ beta)
{
    int idx = blockIdx.x * 256 + threadIdx.x;
    if (idx >= N_NODES * 16) return;
    int o = idx & 15;
    const float invN = 1.0f / (float)N_NODES;
    float mu = stats[o] * invN;
    float var = stats[16 + o] * invN - mu * mu;
    var = fmaxf(var, 0.0f);
    float x = out[idx];
    float y = fmaf(gamma[o] * (x - mu), rsqrtf(var + EPS), beta[o]);
    out[idx] = (y >= 0.0f) ? y : SLOPE * y;
}

extern "C" void kernel_launch(void* const* d_in, const int* in_sizes, int n_in,
                              void* d_out, int out_size, void* d_ws, size_t ws_size,
                              hipStream_t stream)
{
    const float* v = (const float*)d_in[0];
    const float* e = (const float*)d_in[1];
    const int* edge_index = (const int*)d_in[2];
    const float* enet_w = (const float*)d_in[3];
    const float* enet_b = (const float*)d_in[4];
    const float* root = (const float*)d_in[5];
    const float* bias = (const float*)d_in[6];
    const float* gamma = (const float*)d_in[7];
    const float* beta = (const float*)d_in[8];
    float* out = (float*)d_out;

    char* ws = (char*)d_ws;
    Pay*   pay     = (Pay*)ws;     ws += (size_t)N_NODES * CAP * sizeof(Pay); // 64 MB
    float* S       = (float*)ws;   ws += (size_t)N_NODES * 80 * 4;            // 32 MB
    int*   cnt     = (int*)ws;     ws += (size_t)N_NODES * 4;
    float* stats   = (float*)ws;   ws += 32 * 4;
    int*   ovf_cnt = (int*)ws;     ws += 4;
    int*   ovf     = (int*)ws;

    // zero cnt + stats + ovf_cnt (contiguous)
    hipMemsetAsync(cnt, 0, (size_t)N_NODES * 4 + 32 * 4 + 4, stream);

    payload_kernel<<<(N_EDGES + 255) / 256, 256, 0, stream>>>(
        edge_index, e, cnt, pay, ovf, ovf_cnt);
    gather_s_kernel<<<GBLK, 320, 0, stream>>>(v, pay, cnt, S);
    ovf_kernel<<<128, 256, 0, stream>>>(v, edge_index, e, ovf, ovf_cnt, S);
    node_kernel<<<NBLK, 256, 0, stream>>>(
        v, S, cnt, enet_w, enet_b, root, bias, out, stats);
    final_kernel<<<(N_NODES * 16 + 255) / 256, 256, 0, stream>>>(
        out, stats, gamma, beta);
}